// Round 6
// baseline (129.379 us; speedup 1.0000x reference)
//
#include <hip/hip_runtime.h>
#include <cstdint>
#include <cstddef>

typedef __bf16 bf16x8 __attribute__((ext_vector_type(8)));
typedef float f32x4 __attribute__((ext_vector_type(4)));

#define MFMA16(a, b, c) __builtin_amdgcn_mfma_f32_16x16x32_bf16(a, b, c, 0, 0, 0)

static __device__ __forceinline__ bf16x8 ld_bf16x8(const __bf16* p) {
    return *reinterpret_cast<const bf16x8*>(p);
}

static __device__ __forceinline__ void async_cp16(const __bf16* g, __bf16* l) {
    __builtin_amdgcn_global_load_lds((const __attribute__((address_space(1))) void*)g,
                                     (__attribute__((address_space(3))) void*)l, 16, 0, 0);
}

template <int N>
static __device__ __forceinline__ void wait_vmcnt() {
    asm volatile("s_waitcnt vmcnt(%0)" ::"n"(N) : "memory");
}

static __device__ __forceinline__ void barrier_pinned() {
    __builtin_amdgcn_sched_barrier(0);
    __builtin_amdgcn_s_barrier();
    __builtin_amdgcn_sched_barrier(0);
}

// ---------------- f32 -> bf16 convert (8 elems/thread) ----------------
__global__ void cvt_kernel(const float* __restrict__ src, __bf16* __restrict__ dst, int n8) {
    int i = blockIdx.x * blockDim.x + threadIdx.x;
    if (i >= n8) return;
    const float4* s4 = reinterpret_cast<const float4*>(src) + (size_t)i * 2;
    float4 a = s4[0], b = s4[1];
    bf16x8 o;
    o[0] = (__bf16)a.x; o[1] = (__bf16)a.y; o[2] = (__bf16)a.z; o[3] = (__bf16)a.w;
    o[4] = (__bf16)b.x; o[5] = (__bf16)b.y; o[6] = (__bf16)b.z; o[7] = (__bf16)b.w;
    reinterpret_cast<bf16x8*>(dst)[i] = o;
}

// ---------------- transpose-convert: in [K][N] f32 -> out [N][K] bf16 ----------------
__global__ __launch_bounds__(256) void tcvt_kernel(const float* __restrict__ in,
                                                   __bf16* __restrict__ out, int K, int N) {
    __shared__ __bf16 T[64][72];
    const int k0 = blockIdx.y * 64, n0 = blockIdx.x * 64;
    const int t = threadIdx.x;
    const int col = (t & 15) << 2;
    const int rowb = t >> 4;
    #pragma unroll
    for (int i = 0; i < 4; i++) {
        int row = i * 16 + rowb;
        float4 v = *reinterpret_cast<const float4*>(&in[(size_t)(k0 + row) * N + n0 + col]);
        T[col + 0][row] = (__bf16)v.x;
        T[col + 1][row] = (__bf16)v.y;
        T[col + 2][row] = (__bf16)v.z;
        T[col + 3][row] = (__bf16)v.w;
    }
    __syncthreads();
    const int oc = (t & 7) << 3;
    const int orb = t >> 3;
    #pragma unroll
    for (int i = 0; i < 2; i++) {
        int r = i * 32 + orb;
        bf16x8 v = *reinterpret_cast<bf16x8*>(&T[r][oc]);
        *reinterpret_cast<bf16x8*>(&out[(size_t)(n0 + r) * K + k0 + oc]) = v;
    }
}

// ================= 8-phase 256x256 mainloop (m201-style port) =================
// A: [M][K] bf16, Bt: [N][K] bf16. BK=64. 512 threads = 8 waves (2M x 4N).
// LDS: 2 bufs x {Ak0, Ak1, Bk0, Bk1} halves of 8192 elems (16KB) = 128KB.
//   half layout: [256 rows][32 k], row = 64B; chunk swizzle: slot-chunk cs holds
//   logical chunk cl = cs ^ ((row>>1)&3)  (involution; readers apply same XOR).
// Per phase: 4-8 ds_read_b128; stage one half (2 x global_load_lds dwordx4);
//   barrier; setprio(1); 16 MFMA; setprio(0); barrier.
// vmcnt(6) certification at end of phases 3 and 7 only (tail: vmcnt(0)).

template <int BUF, int KS, int MH>
static __device__ __forceinline__ void ldA(const __bf16* lds, int aRow, int ch, bf16x8 (&af)[4]) {
    #pragma unroll
    for (int mi = 0; mi < 4; mi++)
        af[mi] = ld_bf16x8(&lds[BUF * 32768 + KS * 8192 + (aRow + (MH * 4 + mi) * 16) * 32 + ch * 8]);
}

template <int BUF, int KS>
static __device__ __forceinline__ void ldB(const __bf16* lds, int bRow, int ch, bf16x8 (&bf)[4]) {
    #pragma unroll
    for (int n = 0; n < 4; n++)
        bf[n] = ld_bf16x8(&lds[BUF * 32768 + 16384 + KS * 8192 + (bRow + n * 16) * 32 + ch * 8]);
}

template <int MH>
static __device__ __forceinline__ void mm16(const bf16x8 (&af)[4], const bf16x8 (&bf)[4],
                                            f32x4 (&acc)[8][4]) {
    __builtin_amdgcn_s_setprio(1);
    #pragma unroll
    for (int mi = 0; mi < 4; mi++) {
        #pragma unroll
        for (int n = 0; n < 4; n++) {
            acc[MH * 4 + mi][n] = MFMA16(af[mi], bf[n], acc[MH * 4 + mi][n]);
        }
    }
    __builtin_amdgcn_s_setprio(0);
}

__device__ __forceinline__ void mloop8(const __bf16* __restrict__ A,
                                       const __bf16* __restrict__ Bt,
                                       int K, int row0, int col0,
                                       __bf16* lds, f32x4 (&acc)[8][4]) {
    const int tid = threadIdx.x, l = tid & 63, w = tid >> 6;
    const int wm = w >> 2, wn = w & 3;
    const int fr = l & 15;
    const int ch = (l >> 4) ^ ((fr >> 1) & 3);  // swizzled read chunk (lane-const)
    const int NT = K >> 6;

    // staging geometry: g = j*512 + tid; row = g>>2, slot-chunk = g&3,
    // source logical chunk = slot ^ ((row>>1)&3)
    const int g0 = tid, g1 = tid + 512;
    const int r0s = g0 >> 2, c0 = (((g0 & 3) ^ ((r0s >> 1) & 3)) << 3);
    const int r1s = g1 >> 2, c1 = (((g1 & 3) ^ ((r1s >> 1) & 3)) << 3);
    const int d0 = g0 * 8, d1 = g1 * 8;

    const int aRow = wm * 128 + fr;
    const int bRow = wn * 64 + fr;

    auto stg = [&](const __bf16* M, int rb, int ktile, int ksh, int dstoff) {
        const __bf16* base = M + (size_t)ktile * 64 + ksh * 32;
        async_cp16(base + (size_t)(rb + r0s) * K + c0, lds + dstoff + d0);
        async_cp16(base + (size_t)(rb + r1s) * K + c1, lds + dstoff + d1);
    };

    // prologue: t0 {Bk0, Ak0, Bk1, Ak1} -> buf0, t1 {Bk0, Ak0, Bk1} -> buf1
    stg(Bt, col0, 0, 0, 16384);
    stg(A,  row0, 0, 0, 0);
    stg(Bt, col0, 0, 1, 16384 + 8192);
    stg(A,  row0, 0, 1, 8192);
    stg(Bt, col0, 1, 0, 32768 + 16384);
    stg(A,  row0, 1, 0, 32768);
    stg(Bt, col0, 1, 1, 32768 + 16384 + 8192);
    wait_vmcnt<6>();
    barrier_pinned();

    bf16x8 af[4], bf[4];
    const int NI = NT >> 1;
    for (int i = 0; i < NI; ++i) {
        const int t0 = 2 * i, t1 = 2 * i + 1;
        const bool s0 = (t0 + 2) < NT, s1 = (t1 + 2) < NT;

        // p0: tile t0 (buf0) mh0 ks0 + B(ks0); stage t1.Ak1 -> buf1
        ldA<0, 0, 0>(lds, aRow, ch, af);
        ldB<0, 0>(lds, bRow, ch, bf);
        stg(A, row0, t1, 1, 32768 + 8192);
        barrier_pinned();
        mm16<0>(af, bf, acc);
        barrier_pinned();
        // p1: mh1 ks0; stage (t0+2).Bk0 -> buf0
        ldA<0, 0, 1>(lds, aRow, ch, af);
        if (s0) stg(Bt, col0, t0 + 2, 0, 16384);
        barrier_pinned();
        mm16<1>(af, bf, acc);
        barrier_pinned();
        // p2: mh0 ks1 + B(ks1); stage (t0+2).Ak0
        ldA<0, 1, 0>(lds, aRow, ch, af);
        ldB<0, 1>(lds, bRow, ch, bf);
        if (s0) stg(A, row0, t0 + 2, 0, 0);
        barrier_pinned();
        mm16<0>(af, bf, acc);
        barrier_pinned();
        // p3: mh1 ks1; stage (t0+2).Bk1; CERT
        ldA<0, 1, 1>(lds, aRow, ch, af);
        if (s0) {
            stg(Bt, col0, t0 + 2, 1, 16384 + 8192);
            wait_vmcnt<6>();
        } else {
            wait_vmcnt<0>();
        }
        barrier_pinned();
        mm16<1>(af, bf, acc);
        barrier_pinned();
        // p4: tile t1 (buf1) mh0 ks0 + B; stage (t0+2).Ak1
        ldA<1, 0, 0>(lds, aRow, ch, af);
        ldB<1, 0>(lds, bRow, ch, bf);
        if (s0) stg(A, row0, t0 + 2, 1, 8192);
        barrier_pinned();
        mm16<0>(af, bf, acc);
        barrier_pinned();
        // p5: mh1 ks0; stage (t1+2).Bk0 -> buf1
        ldA<1, 0, 1>(lds, aRow, ch, af);
        if (s1) stg(Bt, col0, t1 + 2, 0, 32768 + 16384);
        barrier_pinned();
        mm16<1>(af, bf, acc);
        barrier_pinned();
        // p6: mh0 ks1 + B(ks1); stage (t1+2).Ak0
        ldA<1, 1, 0>(lds, aRow, ch, af);
        ldB<1, 1>(lds, bRow, ch, bf);
        if (s1) stg(A, row0, t1 + 2, 0, 32768);
        barrier_pinned();
        mm16<0>(af, bf, acc);
        barrier_pinned();
        // p7: mh1 ks1; stage (t1+2).Bk1; CERT
        ldA<1, 1, 1>(lds, aRow, ch, af);
        if (s1) {
            stg(Bt, col0, t1 + 2, 1, 32768 + 16384 + 8192);
            wait_vmcnt<6>();
        } else {
            wait_vmcnt<0>();
        }
        barrier_pinned();
        mm16<1>(af, bf, acc);
        barrier_pinned();
    }
}

// ---------------- QKV GEMM: x(4096x1024) @ w_attn^T(3072x1024) + b_attn ----------------
__global__ __launch_bounds__(512, 2) void gemm_qkv_kernel(const __bf16* __restrict__ xb,
                                                          const __bf16* __restrict__ wabt,
                                                          const float* __restrict__ bias,
                                                          __bf16* __restrict__ qb,
                                                          __bf16* __restrict__ kb,
                                                          __bf16* __restrict__ vt,
                                                          float* __restrict__ present) {
    __shared__ __bf16 lds[2 * 32768];  // 128 KB
    f32x4 acc[8][4] = {};

    // bijective XCD swizzle (192 % 8 == 0), column-major tile order
    const int wg = (blockIdx.x & 7) * 24 + (blockIdx.x >> 3);
    const int by = wg & 15, bx = wg >> 4;
    const int row0 = by * 256, col0 = bx * 256;

    mloop8(xb, wabt, 1024, row0, col0, lds, acc);

    const int l = threadIdx.x & 63, w = threadIdx.x >> 6;
    const int wm = w >> 2, wn = w & 3;
    const int part = col0 >> 10;  // uniform per block (1024 = 4 x 256)
    #pragma unroll
    for (int n = 0; n < 4; n++) {
        int col = col0 + wn * 64 + n * 16 + (l & 15);
        int hh = (col >> 6) & 15;
        int dd = col & 63;
        float bv = bias[col];
        #pragma unroll
        for (int m = 0; m < 8; m++) {
            #pragma unroll
            for (int r = 0; r < 4; r++) {
                int row = row0 + wm * 128 + m * 16 + ((l >> 4) << 2) + r;
                int bb = row >> 11, ss = row & 2047;
                float val = acc[m][n][r] + bv;
                size_t qi = (((size_t)(bb * 16 + hh)) * 2048 + ss) * 64 + dd;
                if (part == 0) {
                    qb[qi] = (__bf16)val;
                } else if (part == 1) {
                    kb[qi] = (__bf16)val;
                    present[(((size_t)((bb * 2 + 0) * 16 + hh)) * 2048 + ss) * 64 + dd] = val;
                } else {
                    vt[(((size_t)(bb * 16 + hh)) * 64 + dd) * 2048 + ss] = (__bf16)val;
                    present[(((size_t)((bb * 2 + 1) * 16 + hh)) * 2048 + ss) * 64 + dd] = val;
                }
            }
        }
    }
}

// ---------------- 2-phase mainloop (kept for proj) ----------------
template <int BM, int BN, int WM, int WN>
__device__ __forceinline__ void mainloop2(const __bf16* __restrict__ A,
                                          const __bf16* __restrict__ Bt,
                                          int K, int row0, int col0,
                                          __bf16* lds,
                                          f32x4 (&acc)[BM / WM / 16][BN / WN / 16]) {
    constexpr int MR = BM / WM / 16, NR = BN / WN / 16;
    constexpr int AE = BM * 32;
    constexpr int BUFE = AE + BN * 32;
    constexpr int AI = BM / 16;
    constexpr int BI = BN / 16;
    constexpr int APW = AI / 8;
    constexpr int BPW = BI / 8;
    const int tid = threadIdx.x, l = tid & 63, w = tid >> 6;
    const int wm = w / WN, wn = w % WN;
    const int lr = l >> 2, lc = (l & 3) << 3;
    const int fr = l & 15, fc = (l >> 4) << 3;

    const size_t arow = (size_t)(row0 + lr) * K + lc;
    const size_t brow = (size_t)(col0 + lr) * K + lc;
    const int nt = K >> 5;

    auto stage = [&](int t, int buf) {
        const int k0 = t << 5;
        const int bb = buf * BUFE;
        #pragma unroll
        for (int j = 0; j < APW; j++) {
            const int mi = w * APW + j;
            async_cp16(A + arow + (size_t)mi * 16 * K + k0, lds + bb + mi * 512 + l * 8);
        }
        #pragma unroll
        for (int j = 0; j < BPW; j++) {
            const int ni = w * BPW + j;
            async_cp16(Bt + brow + (size_t)ni * 16 * K + k0, lds + bb + AE + ni * 512 + l * 8);
        }
    };

    stage(0, 0);
    stage(1, 1);

    const int aoff = (wm * (BM / WM) + fr) * 32 + fc;
    const int boff = AE + (wn * (BN / WN) + fr) * 32 + fc;

    int p = 0;
    for (int t = 0; t < nt; ++t) {
        if (t + 1 < nt) {
            wait_vmcnt<APW + BPW>();  // certify tile t fully landed (this wave's loads)
        } else {
            wait_vmcnt<0>();
        }
        barrier_pinned();
        if (t + 2 < nt) {
            int p2 = p + 2; if (p2 >= 3) p2 -= 3;
            stage(t + 2, p2);
        }
        const int cb = p * BUFE;
        bf16x8 af[MR], bfv[NR];
        #pragma unroll
        for (int m = 0; m < MR; m++) af[m] = ld_bf16x8(&lds[cb + aoff + m * 512]);
        #pragma unroll
        for (int n = 0; n < NR; n++) bfv[n] = ld_bf16x8(&lds[cb + boff + n * 512]);
        __builtin_amdgcn_s_setprio(1);
        #pragma unroll
        for (int m = 0; m < MR; m++) {
            #pragma unroll
            for (int n = 0; n < NR; n++) {
                acc[m][n] = MFMA16(af[m], bfv[n], acc[m][n]);
            }
        }
        __builtin_amdgcn_s_setprio(0);
        asm volatile("s_waitcnt lgkmcnt(0)" ::: "memory");
        __builtin_amdgcn_sched_barrier(0);
        p = (p == 2) ? 0 : p + 1;
    }
}

// ---------------- Proj GEMM: a(4096x1024) @ w_proj^T(1024x1024) + b_proj ----------------
__global__ __launch_bounds__(512, 2) void gemm_proj_kernel(const __bf16* __restrict__ ab,
                                                           const __bf16* __restrict__ wpbt,
                                                           const float* __restrict__ bias,
                                                           float* __restrict__ out) {
    __shared__ __bf16 lds[3 * (128 * 32 + 128 * 32)];
    f32x4 acc[2][4] = {};
    const int row0 = blockIdx.y * 128, col0 = blockIdx.x * 128;
    mainloop2<128, 128, 4, 2>(ab, wpbt, 1024, row0, col0, lds, acc);

    const int lane = threadIdx.x & 63, w = threadIdx.x >> 6;
    const int wm = w >> 1, wn = w & 1;
    #pragma unroll
    for (int n = 0; n < 4; n++) {
        int col = col0 + wn * 64 + n * 16 + (lane & 15);
        float bv = bias[col];
        #pragma unroll
        for (int m = 0; m < 2; m++) {
            #pragma unroll
            for (int r = 0; r < 4; r++) {
                int row = row0 + wm * 32 + m * 16 + ((lane >> 4) << 2) + r;
                out[(size_t)row * 1024 + col] = acc[m][n][r] + bv;
            }
        }
    }
}

// ---------------- sliding-window causal flash attention ----------------
__global__ __launch_bounds__(256) void attn_kernel(const __bf16* __restrict__ qb,
                                                   const __bf16* __restrict__ kb,
                                                   const __bf16* __restrict__ vtb,
                                                   __bf16* __restrict__ ab) {
    __shared__ __bf16 Pls[4][16 * 40];
    const int bh = blockIdx.x >> 5;
    const int qt = blockIdx.x & 31;
    const int lane = threadIdx.x & 63, wid = threadIdx.x >> 6;
    const int q0w = qt * 64 + wid * 16;

    const __bf16* Qh = qb + (size_t)bh * 2048 * 64;
    const __bf16* Kh = kb + (size_t)bh * 2048 * 64;
    const __bf16* Vt = vtb + (size_t)bh * 64 * 2048;
    __bf16* Pw = &Pls[wid][0];

    bf16x8 qf[2];
    {
        int qr = q0w + (lane & 15);
        const __bf16* qp = Qh + (size_t)qr * 64 + ((lane >> 4) << 3);
        qf[0] = ld_bf16x8(qp);
        qf[1] = ld_bf16x8(qp + 32);
    }

    f32x4 o[4];
    #pragma unroll
    for (int dt = 0; dt < 4; dt++) o[dt] = (f32x4){0.f, 0.f, 0.f, 0.f};
    float mrun[4] = {-1e30f, -1e30f, -1e30f, -1e30f};
    float srun[4] = {0.f, 0.f, 0.f, 0.f};

    const float scale = 0.125f;
    int klo = q0w - 255;
    int kt0 = klo > 0 ? (klo & ~31) : 0;

    for (int kt = kt0; kt <= q0w + 15; kt += 32) {
        f32x4 s[2];
        #pragma unroll
        for (int kc = 0; kc < 2; kc++) {
            int krow = kt + kc * 16 + (lane & 15);
            const __bf16* kp = Kh + (size_t)krow * 64 + ((lane >> 4) << 3);
            bf16x8 kf0 = ld_bf16x8(kp);
            bf16x8 kf1 = ld_bf16x8(kp + 32);
            f32x4 a = (f32x4){0.f, 0.f, 0.f, 0.f};
            a = MFMA16(qf[0], kf0, a);
            a = MFMA16(qf[1], kf1, a);
            s[kc] = a;
        }
        float p0v[4], p1v[4], factor[4];
        #pragma unroll
        for (int r = 0; r < 4; r++) {
            int q = q0w + ((lane >> 4) << 2) + r;
            int k0i = kt + (lane & 15);
            int k1i = k0i + 16;
            bool ok0 = (k0i <= q) && (k0i > q - 256);
            bool ok1 = (k1i <= q) && (k1i > q - 256);
            float s0 = ok0 ? s[0][r] * scale : -1e30f;
            float s1 = ok1 ? s[1][r] * scale : -1e30f;
            float mx = fmaxf(s0, s1);
            #pragma unroll
            for (int off = 1; off < 16; off <<= 1) mx = fmaxf(mx, __shfl_xor(mx, off));
            float mn = fmaxf(mrun[r], mx);
            float f = __expf(mrun[r] - mn);
            float p0 = ok0 ? __expf(s0 - mn) : 0.f;
            float p1 = ok1 ? __expf(s1 - mn) : 0.f;
            float ps = p0 + p1;
            #pragma unroll
            for (int off = 1; off < 16; off <<= 1) ps += __shfl_xor(ps, off);
            srun[r] = srun[r] * f + ps;
            mrun[r] = mn;
            factor[r] = f;
            p0v[r] = p0;
            p1v[r] = p1;
        }
        #pragma unroll
        for (int dt = 0; dt < 4; dt++) {
            #pragma unroll
            for (int r = 0; r < 4; r++) o[dt][r] *= factor[r];
        }
        #pragma unroll
        for (int r = 0; r < 4; r++) {
            int qrow = ((lane >> 4) << 2) + r;
            Pw[qrow * 40 + (lane & 15)] = (__bf16)p0v[r];
            Pw[qrow * 40 + 16 + (lane & 15)] = (__bf16)p1v[r];
        }
        asm volatile("s_waitcnt lgkmcnt(0)" ::: "memory");
        bf16x8 pf = ld_bf16x8(&Pw[(lane & 15) * 40 + ((lane >> 4) << 3)]);
        #pragma unroll
        for (int dt = 0; dt < 4; dt++) {
            bf16x8 vf = ld_bf16x8(&Vt[(size_t)(dt * 16 + (lane & 15)) * 2048 + kt + ((lane >> 4) << 3)]);
            o[dt] = MFMA16(pf, vf, o[dt]);
        }
    }

    const int bb = bh >> 4, hh = bh & 15;
    #pragma unroll
    for (int r = 0; r < 4; r++) {
        int q = q0w + ((lane >> 4) << 2) + r;
        float inv = 1.f / srun[r];
        size_t base = ((size_t)bb * 2048 + q) * 1024 + hh * 64;
        #pragma unroll
        for (int dt = 0; dt < 4; dt++) {
            ab[base + dt * 16 + (lane & 15)] = (__bf16)(o[dt][r] * inv);
        }
    }
}

// ---------------- launch ----------------
extern "C" void kernel_launch(void* const* d_in, const int* in_sizes, int n_in,
                              void* d_out, int out_size, void* d_ws, size_t ws_size,
                              hipStream_t stream) {
    const float* x = (const float*)d_in[0];
    const float* w_attn = (const float*)d_in[1];
    const float* b_attn = (const float*)d_in[2];
    const float* w_proj = (const float*)d_in[3];
    const float* b_proj = (const float*)d_in[4];

    float* out = (float*)d_out;
    float* present = out + (size_t)2 * 2048 * 1024;

    char* w = (char*)d_ws;
    __bf16* xb   = (__bf16*)(w);
    __bf16* wabt = (__bf16*)(w + 8388608);
    __bf16* wpbt = (__bf16*)(w + 14680064);
    __bf16* qb   = (__bf16*)(w + 16777216);
    __bf16* kb   = (__bf16*)(w + 25165824);
    __bf16* vt   = (__bf16*)(w + 33554432);
    __bf16* ab   = xb;

    cvt_kernel<<<2048, 256, 0, stream>>>(x, xb, 524288);
    tcvt_kernel<<<dim3(48, 16), 256, 0, stream>>>(w_attn, wabt, 1024, 3072);
    tcvt_kernel<<<dim3(16, 16), 256, 0, stream>>>(w_proj, wpbt, 1024, 1024);

    gemm_qkv_kernel<<<192, 512, 0, stream>>>(xb, wabt, b_attn, qb, kb, vt, present);

    attn_kernel<<<1024, 256, 0, stream>>>(qb, kb, vt, ab);

    gemm_proj_kernel<<<dim3(8, 32), 512, 0, stream>>>(ab, wpbt, b_proj, out);
}

// Round 7
// 121.724 us; speedup vs baseline: 1.0629x; 1.0629x over previous
//
#include <hip/hip_runtime.h>
#include <cstdint>
#include <cstddef>

typedef __bf16 bf16x8 __attribute__((ext_vector_type(8)));
typedef float f32x4 __attribute__((ext_vector_type(4)));

#define MFMA16(a, b, c) __builtin_amdgcn_mfma_f32_16x16x32_bf16(a, b, c, 0, 0, 0)

static __device__ __forceinline__ bf16x8 ld_bf16x8(const __bf16* p) {
    return *reinterpret_cast<const bf16x8*>(p);
}

static __device__ __forceinline__ void async_cp16(const __bf16* g, __bf16* l) {
    __builtin_amdgcn_global_load_lds((const __attribute__((address_space(1))) void*)g,
                                     (__attribute__((address_space(3))) void*)l, 16, 0, 0);
}

template <int N>
static __device__ __forceinline__ void wait_vmcnt() {
    asm volatile("s_waitcnt vmcnt(%0)" ::"n"(N) : "memory");
}

static __device__ __forceinline__ void barrier_pinned() {
    __builtin_amdgcn_sched_barrier(0);
    __builtin_amdgcn_s_barrier();
    __builtin_amdgcn_sched_barrier(0);
}

// ---- DPP 16-lane rotate-reduce (pure VALU, no DS pipe) ----
// row_ror:N rotates within each 16-lane row; steps 1,2,4,8 give every lane the
// full 16-lane reduction (cyclic rotate-reduce).
template <int CTRL>
static __device__ __forceinline__ float dppmv(float x) {
    return __builtin_bit_cast(float, __builtin_amdgcn_update_dpp(
        0, __builtin_bit_cast(int, x), CTRL, 0xF, 0xF, true));
}
static __device__ __forceinline__ float rmax16(float x) {
    x = fmaxf(x, dppmv<0x121>(x));  // row_ror:1
    x = fmaxf(x, dppmv<0x122>(x));  // row_ror:2
    x = fmaxf(x, dppmv<0x124>(x));  // row_ror:4
    x = fmaxf(x, dppmv<0x128>(x));  // row_ror:8
    return x;
}
static __device__ __forceinline__ float rsum16(float x) {
    x += dppmv<0x121>(x);
    x += dppmv<0x122>(x);
    x += dppmv<0x124>(x);
    x += dppmv<0x128>(x);
    return x;
}

// ---------------- f32 -> bf16 convert (8 elems/thread) ----------------
__global__ void cvt_kernel(const float* __restrict__ src, __bf16* __restrict__ dst, int n8) {
    int i = blockIdx.x * blockDim.x + threadIdx.x;
    if (i >= n8) return;
    const float4* s4 = reinterpret_cast<const float4*>(src) + (size_t)i * 2;
    float4 a = s4[0], b = s4[1];
    bf16x8 o;
    o[0] = (__bf16)a.x; o[1] = (__bf16)a.y; o[2] = (__bf16)a.z; o[3] = (__bf16)a.w;
    o[4] = (__bf16)b.x; o[5] = (__bf16)b.y; o[6] = (__bf16)b.z; o[7] = (__bf16)b.w;
    reinterpret_cast<bf16x8*>(dst)[i] = o;
}

// ---------------- transpose-convert: in [K][N] f32 -> out [N][K] bf16 ----------------
__global__ __launch_bounds__(256) void tcvt_kernel(const float* __restrict__ in,
                                                   __bf16* __restrict__ out, int K, int N) {
    __shared__ __bf16 T[64][72];
    const int k0 = blockIdx.y * 64, n0 = blockIdx.x * 64;
    const int t = threadIdx.x;
    const int col = (t & 15) << 2;
    const int rowb = t >> 4;
    #pragma unroll
    for (int i = 0; i < 4; i++) {
        int row = i * 16 + rowb;
        float4 v = *reinterpret_cast<const float4*>(&in[(size_t)(k0 + row) * N + n0 + col]);
        T[col + 0][row] = (__bf16)v.x;
        T[col + 1][row] = (__bf16)v.y;
        T[col + 2][row] = (__bf16)v.z;
        T[col + 3][row] = (__bf16)v.w;
    }
    __syncthreads();
    const int oc = (t & 7) << 3;
    const int orb = t >> 3;
    #pragma unroll
    for (int i = 0; i < 2; i++) {
        int r = i * 32 + orb;
        bf16x8 v = *reinterpret_cast<bf16x8*>(&T[r][oc]);
        *reinterpret_cast<bf16x8*>(&out[(size_t)(n0 + r) * K + k0 + oc]) = v;
    }
}

// ---------------- R3 2-phase double-buffered mainloop (measured 53us on qkv) ----------
// C(128x128) += A(128xK) * Bt(128xK)^T. 256 threads, 4 waves.
__device__ __forceinline__ void gemm_mainloop(const __bf16* __restrict__ A,
                                              const __bf16* __restrict__ Bt,
                                              int K, int row0, int col0,
                                              __bf16* Als, __bf16* Bls, f32x4 acc[4][4]) {
    const int tid = threadIdx.x;
    const int lane = tid & 63;
    const int wid = tid >> 6;
    const int wr = wid >> 1, wc = wid & 1;
    const int r0 = tid >> 2, o0 = (tid & 3) << 3;
    const __bf16* a0 = A + (size_t)(row0 + r0) * K + o0;
    const __bf16* a1 = A + (size_t)(row0 + r0 + 64) * K + o0;
    const __bf16* b0 = Bt + (size_t)(col0 + r0) * K + o0;
    const __bf16* b1 = Bt + (size_t)(col0 + r0 + 64) * K + o0;
    const int loff = tid * 8;
    const int aoff = (wr * 64 + (lane & 15)) * 32 + ((lane >> 4) << 3);
    const int boff = (wc * 64 + (lane & 15)) * 32 + ((lane >> 4) << 3);

    const int nt = K >> 5;
    async_cp16(a0, &Als[loff]);
    async_cp16(a1, &Als[loff + 2048]);
    async_cp16(b0, &Bls[loff]);
    async_cp16(b1, &Bls[loff + 2048]);
    __syncthreads();

    int cur = 0;
    for (int t = 0; t < nt; ++t) {
        if (t + 1 < nt) {
            const int k1 = (t + 1) << 5;
            const int nb = (cur ^ 1) * 4096;
            async_cp16(a0 + k1, &Als[nb + loff]);
            async_cp16(a1 + k1, &Als[nb + loff + 2048]);
            async_cp16(b0 + k1, &Bls[nb + loff]);
            async_cp16(b1 + k1, &Bls[nb + loff + 2048]);
        }
        const int cb = cur * 4096;
        bf16x8 af[4], bfr[4];
        #pragma unroll
        for (int m = 0; m < 4; m++) af[m] = ld_bf16x8(&Als[cb + aoff + m * 512]);
        #pragma unroll
        for (int n = 0; n < 4; n++) bfr[n] = ld_bf16x8(&Bls[cb + boff + n * 512]);
        #pragma unroll
        for (int m = 0; m < 4; m++) {
            #pragma unroll
            for (int n = 0; n < 4; n++) {
                acc[m][n] = MFMA16(af[m], bfr[n], acc[m][n]);
            }
        }
        __syncthreads();
        cur ^= 1;
    }
}

// ---------------- QKV GEMM: x(4096x1024) @ w_attn^T(3072x1024) + b_attn ----------------
__global__ __launch_bounds__(256) void gemm_qkv_kernel(const __bf16* __restrict__ xb,
                                                       const __bf16* __restrict__ wabt,
                                                       const float* __restrict__ bias,
                                                       __bf16* __restrict__ qb,
                                                       __bf16* __restrict__ kb,
                                                       __bf16* __restrict__ vt,
                                                       float* __restrict__ present) {
    __shared__ __bf16 Als[2 * 128 * 32];
    __shared__ __bf16 Bls[2 * 128 * 32];
    f32x4 acc[4][4] = {};
    const int row0 = blockIdx.y * 128, col0 = blockIdx.x * 128;
    gemm_mainloop(xb, wabt, 1024, row0, col0, Als, Bls, acc);

    const int lane = threadIdx.x & 63, wid = threadIdx.x >> 6;
    const int wr = wid >> 1, wc = wid & 1;
    const int part = col0 >> 10;  // uniform per block: 0=q 1=k 2=v
    #pragma unroll
    for (int n = 0; n < 4; n++) {
        int col = col0 + wc * 64 + n * 16 + (lane & 15);
        int hh = (col >> 6) & 15;
        int dd = col & 63;
        float bv = bias[col];
        #pragma unroll
        for (int m = 0; m < 4; m++) {
            #pragma unroll
            for (int r = 0; r < 4; r++) {
                int row = row0 + wr * 64 + m * 16 + ((lane >> 4) << 2) + r;
                int bb = row >> 11, ss = row & 2047;
                float val = acc[m][n][r] + bv;
                size_t qi = (((size_t)(bb * 16 + hh)) * 2048 + ss) * 64 + dd;
                if (part == 0) {
                    qb[qi] = (__bf16)val;
                } else if (part == 1) {
                    kb[qi] = (__bf16)val;
                    present[(((size_t)((bb * 2 + 0) * 16 + hh)) * 2048 + ss) * 64 + dd] = val;
                } else {
                    vt[(((size_t)(bb * 16 + hh)) * 64 + dd) * 2048 + ss] = (__bf16)val;
                    present[(((size_t)((bb * 2 + 1) * 16 + hh)) * 2048 + ss) * 64 + dd] = val;
                }
            }
        }
    }
}

// ---------------- 3-buffer counted-vmcnt mainloop (kept for proj, R6-measured) ----------
template <int BM, int BN, int WM, int WN>
__device__ __forceinline__ void mainloop2(const __bf16* __restrict__ A,
                                          const __bf16* __restrict__ Bt,
                                          int K, int row0, int col0,
                                          __bf16* lds,
                                          f32x4 (&acc)[BM / WM / 16][BN / WN / 16]) {
    constexpr int MR = BM / WM / 16, NR = BN / WN / 16;
    constexpr int AE = BM * 32;
    constexpr int BUFE = AE + BN * 32;
    constexpr int AI = BM / 16;
    constexpr int BI = BN / 16;
    constexpr int APW = AI / 8;
    constexpr int BPW = BI / 8;
    const int tid = threadIdx.x, l = tid & 63, w = tid >> 6;
    const int wm = w / WN, wn = w % WN;
    const int lr = l >> 2, lc = (l & 3) << 3;
    const int fr = l & 15, fc = (l >> 4) << 3;

    const size_t arow = (size_t)(row0 + lr) * K + lc;
    const size_t brow = (size_t)(col0 + lr) * K + lc;
    const int nt = K >> 5;

    auto stage = [&](int t, int buf) {
        const int k0 = t << 5;
        const int bb = buf * BUFE;
        #pragma unroll
        for (int j = 0; j < APW; j++) {
            const int mi = w * APW + j;
            async_cp16(A + arow + (size_t)mi * 16 * K + k0, lds + bb + mi * 512 + l * 8);
        }
        #pragma unroll
        for (int j = 0; j < BPW; j++) {
            const int ni = w * BPW + j;
            async_cp16(Bt + brow + (size_t)ni * 16 * K + k0, lds + bb + AE + ni * 512 + l * 8);
        }
    };

    stage(0, 0);
    stage(1, 1);

    const int aoff = (wm * (BM / WM) + fr) * 32 + fc;
    const int boff = AE + (wn * (BN / WN) + fr) * 32 + fc;

    int p = 0;
    for (int t = 0; t < nt; ++t) {
        if (t + 1 < nt) {
            wait_vmcnt<APW + BPW>();  // certify tile t fully landed
        } else {
            wait_vmcnt<0>();
        }
        barrier_pinned();
        if (t + 2 < nt) {
            int p2 = p + 2; if (p2 >= 3) p2 -= 3;
            stage(t + 2, p2);
        }
        const int cb = p * BUFE;
        bf16x8 af[MR], bfv[NR];
        #pragma unroll
        for (int m = 0; m < MR; m++) af[m] = ld_bf16x8(&lds[cb + aoff + m * 512]);
        #pragma unroll
        for (int n = 0; n < NR; n++) bfv[n] = ld_bf16x8(&lds[cb + boff + n * 512]);
        __builtin_amdgcn_s_setprio(1);
        #pragma unroll
        for (int m = 0; m < MR; m++) {
            #pragma unroll
            for (int n = 0; n < NR; n++) {
                acc[m][n] = MFMA16(af[m], bfv[n], acc[m][n]);
            }
        }
        __builtin_amdgcn_s_setprio(0);
        asm volatile("s_waitcnt lgkmcnt(0)" ::: "memory");
        __builtin_amdgcn_sched_barrier(0);
        p = (p == 2) ? 0 : p + 1;
    }
}

// ---------------- Proj GEMM: a(4096x1024) @ w_proj^T(1024x1024) + b_proj ----------------
__global__ __launch_bounds__(512, 2) void gemm_proj_kernel(const __bf16* __restrict__ ab,
                                                           const __bf16* __restrict__ wpbt,
                                                           const float* __restrict__ bias,
                                                           float* __restrict__ out) {
    __shared__ __bf16 lds[3 * (128 * 32 + 128 * 32)];
    f32x4 acc[2][4] = {};
    const int row0 = blockIdx.y * 128, col0 = blockIdx.x * 128;
    mainloop2<128, 128, 4, 2>(ab, wpbt, 1024, row0, col0, lds, acc);

    const int lane = threadIdx.x & 63, w = threadIdx.x >> 6;
    const int wm = w >> 1, wn = w & 1;
    #pragma unroll
    for (int n = 0; n < 4; n++) {
        int col = col0 + wn * 64 + n * 16 + (lane & 15);
        float bv = bias[col];
        #pragma unroll
        for (int m = 0; m < 2; m++) {
            #pragma unroll
            for (int r = 0; r < 4; r++) {
                int row = row0 + wm * 32 + m * 16 + ((lane >> 4) << 2) + r;
                out[(size_t)row * 1024 + col] = acc[m][n][r] + bv;
            }
        }
    }
}

// ---------------- sliding-window causal flash attention ----------------
// 4 waves/block, 16 q-rows/wave. DPP rotate-reduce softmax (no DS-pipe shuffles),
// wave-uniform clean/dirty tile split, log2-domain exp (native v_exp_f32).
__global__ __launch_bounds__(256) void attn_kernel(const __bf16* __restrict__ qb,
                                                   const __bf16* __restrict__ kb,
                                                   const __bf16* __restrict__ vtb,
                                                   __bf16* __restrict__ ab) {
    __shared__ __bf16 Pls[4][16 * 40];
    const int bh = blockIdx.x >> 5;
    const int qt = blockIdx.x & 31;
    const int lane = threadIdx.x & 63, wid = threadIdx.x >> 6;
    const int q0w = qt * 64 + wid * 16;

    const __bf16* Qh = qb + (size_t)bh * 2048 * 64;
    const __bf16* Kh = kb + (size_t)bh * 2048 * 64;
    const __bf16* Vt = vtb + (size_t)bh * 64 * 2048;
    __bf16* Pw = &Pls[wid][0];

    bf16x8 qf[2];
    {
        int qr = q0w + (lane & 15);
        const __bf16* qp = Qh + (size_t)qr * 64 + ((lane >> 4) << 3);
        qf[0] = ld_bf16x8(qp);
        qf[1] = ld_bf16x8(qp + 32);
    }

    f32x4 o[4];
    #pragma unroll
    for (int dt = 0; dt < 4; dt++) o[dt] = (f32x4){0.f, 0.f, 0.f, 0.f};
    float mrun[4] = {-1e30f, -1e30f, -1e30f, -1e30f};  // log2-domain
    float srun[4] = {0.f, 0.f, 0.f, 0.f};

    const float cl2 = 0.18033688f;  // (1/sqrt(64)) * log2(e)
    int klo = q0w - 255;
    int kt0 = klo > 0 ? (klo & ~31) : 0;

    for (int kt = kt0; kt <= q0w + 15; kt += 32) {
        // ---- scores for 32 keys ----
        f32x4 s[2];
        #pragma unroll
        for (int kc = 0; kc < 2; kc++) {
            int krow = kt + kc * 16 + (lane & 15);
            const __bf16* kp = Kh + (size_t)krow * 64 + ((lane >> 4) << 3);
            bf16x8 kf0 = ld_bf16x8(kp);
            bf16x8 kf1 = ld_bf16x8(kp + 32);
            f32x4 a = (f32x4){0.f, 0.f, 0.f, 0.f};
            a = MFMA16(qf[0], kf0, a);
            a = MFMA16(qf[1], kf1, a);
            s[kc] = a;
        }
        // ---- online softmax (log2-domain, DPP reduces) ----
        const bool clean = (kt >= q0w - 240) && (kt + 31 <= q0w);  // wave-uniform
        float p0v[4], p1v[4], factor[4];
        if (clean) {
            #pragma unroll
            for (int r = 0; r < 4; r++) {
                float s0 = s[0][r] * cl2;
                float s1 = s[1][r] * cl2;
                float mx = rmax16(fmaxf(s0, s1));
                float mn = fmaxf(mrun[r], mx);
                float f = exp2f(mrun[r] - mn);
                float p0 = exp2f(s0 - mn);
                float p1 = exp2f(s1 - mn);
                float ps = rsum16(p0 + p1);
                srun[r] = srun[r] * f + ps;
                mrun[r] = mn;
                factor[r] = f;
                p0v[r] = p0;
                p1v[r] = p1;
            }
        } else {
            #pragma unroll
            for (int r = 0; r < 4; r++) {
                int q = q0w + ((lane >> 4) << 2) + r;
                int k0i = kt + (lane & 15);
                int k1i = k0i + 16;
                bool ok0 = (k0i <= q) && (k0i > q - 256);
                bool ok1 = (k1i <= q) && (k1i > q - 256);
                float s0 = ok0 ? s[0][r] * cl2 : -1e30f;
                float s1 = ok1 ? s[1][r] * cl2 : -1e30f;
                float mx = rmax16(fmaxf(s0, s1));
                float mn = fmaxf(mrun[r], mx);
                float f = exp2f(mrun[r] - mn);
                float p0 = ok0 ? exp2f(s0 - mn) : 0.f;
                float p1 = ok1 ? exp2f(s1 - mn) : 0.f;
                float ps = rsum16(p0 + p1);
                srun[r] = srun[r] * f + ps;
                mrun[r] = mn;
                factor[r] = f;
                p0v[r] = p0;
                p1v[r] = p1;
            }
        }
        #pragma unroll
        for (int dt = 0; dt < 4; dt++) {
            #pragma unroll
            for (int r = 0; r < 4; r++) o[dt][r] *= factor[r];
        }
        // ---- write P to per-wave LDS ----
        #pragma unroll
        for (int r = 0; r < 4; r++) {
            int qrow = ((lane >> 4) << 2) + r;
            Pw[qrow * 40 + (lane & 15)] = (__bf16)p0v[r];
            Pw[qrow * 40 + 16 + (lane & 15)] = (__bf16)p1v[r];
        }
        asm volatile("s_waitcnt lgkmcnt(0)" ::: "memory");
        // ---- PV ----
        bf16x8 pf = ld_bf16x8(&Pw[(lane & 15) * 40 + ((lane >> 4) << 3)]);
        #pragma unroll
        for (int dt = 0; dt < 4; dt++) {
            bf16x8 vf = ld_bf16x8(&Vt[(size_t)(dt * 16 + (lane & 15)) * 2048 + kt + ((lane >> 4) << 3)]);
            o[dt] = MFMA16(pf, vf, o[dt]);
        }
    }

    const int bb = bh >> 4, hh = bh & 15;
    #pragma unroll
    for (int r = 0; r < 4; r++) {
        int q = q0w + ((lane >> 4) << 2) + r;
        float inv = 1.f / srun[r];
        size_t base = ((size_t)bb * 2048 + q) * 1024 + hh * 64;
        #pragma unroll
        for (int dt = 0; dt < 4; dt++) {
            ab[base + dt * 16 + (lane & 15)] = (__bf16)(o[dt][r] * inv);
        }
    }
}

// ---------------- launch ----------------
extern "C" void kernel_launch(void* const* d_in, const int* in_sizes, int n_in,
                              void* d_out, int out_size, void* d_ws, size_t ws_size,
                              hipStream_t stream) {
    const float* x = (const float*)d_in[0];
    const float* w_attn = (const float*)d_in[1];
    const float* b_attn = (const float*)d_in[2];
    const float* w_proj = (const float*)d_in[3];
    const float* b_proj = (const float*)d_in[4];

    float* out = (float*)d_out;
    float* present = out + (size_t)2 * 2048 * 1024;

    char* w = (char*)d_ws;
    __bf16* xb   = (__bf16*)(w);
    __bf16* wabt = (__bf16*)(w + 8388608);
    __bf16* wpbt = (__bf16*)(w + 14680064);
    __bf16* qb   = (__bf16*)(w + 16777216);
    __bf16* kb   = (__bf16*)(w + 25165824);
    __bf16* vt   = (__bf16*)(w + 33554432);
    __bf16* ab   = xb;

    cvt_kernel<<<2048, 256, 0, stream>>>(x, xb, 524288);
    tcvt_kernel<<<dim3(48, 16), 256, 0, stream>>>(w_attn, wabt, 1024, 3072);
    tcvt_kernel<<<dim3(16, 16), 256, 0, stream>>>(w_proj, wpbt, 1024, 1024);

    gemm_qkv_kernel<<<dim3(24, 32), 256, 0, stream>>>(xb, wabt, b_attn, qb, kb, vt, present);

    attn_kernel<<<1024, 256, 0, stream>>>(qb, kb, vt, ab);

    gemm_proj_kernel<<<dim3(8, 32), 512, 0, stream>>>(ab, wpbt, b_proj, out);
}